// Round 9
// baseline (287.624 us; speedup 1.0000x reference)
//
#include <hip/hip_runtime.h>
#include <stdint.h>

// B=4, C=O=320, H=W=64 -> HW=4096, N2=32768 (dconv n<16384, h n>=16384),
// K=2880 (M pad 384), Kf=640.
// K-permutation: kk = g*72 + k*8 + cl, c = g*8+cl (g<40, k<9, cl<8); kkb=kk>>3=g*9+k.
// Sd packed-8 (dconv only): elem(kk,n) at ushort idx (kkb*16384+n)*8 + (kk&7).
// Xp (padded x, h half): [g][b][py 66][px 66][cl 8] bf16; interior = x, halo = 0.
// C packed-8: elem(o,n2) at (o>>3)*32768*8 + n2*8 + (o&7).
// LDS A-tile layout (conflict-free): chunk (m, kq) at (kq*128 + m)*8 ushorts.
//
// ws layout (bytes):
//   Cc 0..25,165,824 | Wr ..27,377,664 | W2 ..27,869,184 | oI ..28,164,096
//   oWt ..28,753,920 | hoffG ..28,758,016 | Xp ..39,909,376 | Sd ..134,281,216

typedef __attribute__((ext_vector_type(4))) float f32x4;
typedef __attribute__((ext_vector_type(8))) short bf16x8;

typedef __attribute__((address_space(1))) const unsigned int uint_as1;
typedef __attribute__((address_space(3))) unsigned int uint_as3;

__device__ __forceinline__ void gl_lds16(const void* g, void* l) {
    __builtin_amdgcn_global_load_lds((uint_as1*)g, (uint_as3*)l, 16, 0, 0);
}

__device__ __forceinline__ unsigned short f2b(float f) {
    union { float f; uint32_t u; } v; v.f = f;
    uint32_t r = (v.u + 0x7FFFu + ((v.u >> 16) & 1u)) >> 16;
    return (unsigned short)r;
}
__device__ __forceinline__ float b2f(unsigned short h) {
    union { uint32_t u; float f; } v; v.u = ((uint32_t)h) << 16;
    return v.f;
}
__device__ __forceinline__ float b2f_lo(uint32_t u) {
    union { uint32_t u; float f; } v; v.u = u << 16;
    return v.f;
}
__device__ __forceinline__ float b2f_hi(uint32_t u) {
    union { uint32_t u; float f; } v; v.u = u & 0xFFFF0000u;
    return v.f;
}
__device__ __forceinline__ uint32_t pack2(float lo, float hi) {
    return (uint32_t)f2b(lo) | ((uint32_t)f2b(hi) << 16);
}

// ---------------------------------------------------------------------------
// Fused prep (round-7/8-verified). [0,144) bilinear; [144,4464) Wr;
// [4464,5424) W2; [5424,5426) hoffG; [5426,6107) zero Xp.
__global__ __launch_bounds__(256) void k_prep(const float* __restrict__ off,
                                              const float* __restrict__ w,
                                              const float* __restrict__ wd,
                                              const float* __restrict__ wu,
                                              uint32_t* __restrict__ oIdx,
                                              float* __restrict__ oW,
                                              unsigned short* __restrict__ Wr,
                                              unsigned short* __restrict__ W2,
                                              int* __restrict__ hoffG,
                                              unsigned short* __restrict__ Xp)
{
    const int bx = blockIdx.x, tid = threadIdx.x;
    if (bx < 144) {
        int gid = bx * 256 + tid;                    // 9*4096 exact
        int k = gid >> 12;
        int p = gid & 4095;
        int i = p >> 6, j = p & 63;
        float dy = off[(2 * k) * 4096 + p];
        float dx = off[(2 * k + 1) * 4096 + p];
        float py = (float)(i - 1 + k / 3) + dy;
        float px = (float)(j - 1 + k % 3) + dx;
        float fy = floorf(py), fx = floorf(px);
        float wy = py - fy, wx = px - fx;
        fy = fminf(fmaxf(fy, -100.f), 100.f);
        fx = fminf(fmaxf(fx, -100.f), 100.f);
        int y0 = (int)fy, x0 = (int)fx;
        float vy0 = (y0 >= 0 && y0 < 64) ? 1.f : 0.f;
        float vy1 = (y0 >= -1 && y0 < 63) ? 1.f : 0.f;
        float vx0 = (x0 >= 0 && x0 < 64) ? 1.f : 0.f;
        float vx1 = (x0 >= -1 && x0 < 63) ? 1.f : 0.f;
        float w00 = (1.f - wy) * (1.f - wx) * vy0 * vx0;
        float w01 = (1.f - wy) * wx * vy0 * vx1;
        float w10 = wy * (1.f - wx) * vy1 * vx0;
        float w11 = wy * wx * vy1 * vx1;
        int ya = min(max(y0, 0), 63), yb = min(max(y0 + 1, 0), 63);
        int xa = min(max(x0, 0), 63), xb = min(max(x0 + 1, 0), 63);
        oIdx[gid * 2 + 0] = (uint32_t)(ya * 64 + xa) | ((uint32_t)(ya * 64 + xb) << 16);
        oIdx[gid * 2 + 1] = (uint32_t)(yb * 64 + xa) | ((uint32_t)(yb * 64 + xb) << 16);
        oW[gid * 4 + 0] = w00;
        oW[gid * 4 + 1] = w01;
        oW[gid * 4 + 2] = w10;
        oW[gid * 4 + 3] = w11;
    } else if (bx < 4464) {
        int gid = (bx - 144) * 256 + tid;            // 384*2880 exact
        int o = gid / 2880, kk = gid % 2880;
        int g = kk / 72, r = kk % 72, k = r >> 3, cl = r & 7, c = g * 8 + cl;
        float v = (o < 320) ? w[((size_t)o * 320 + c) * 9 + k] : 0.f;
        Wr[gid] = f2b(v);
    } else if (bx < 5424) {
        int gid = (bx - 4464) * 256 + tid;           // 384*640 exact
        int o = gid / 640, kk2 = gid % 640;
        float acc = 0.f;
        if (o < 320) {
            for (int l = 0; l < 320; ++l)
                acc += wu[o * 320 + l] * wd[l * 640 + kk2];
        }
        W2[gid] = f2b(acc);
    } else if (bx < 5426) {
        int kkb = (bx - 5424) * 256 + tid;           // 360 entries
        if (kkb < 360) {
            int g = kkb / 9, k = kkb % 9;
            hoffG[kkb] = (g * 17424 + (k / 3) * 66 + (k % 3)) * 8; // ushort units
        }
    } else {
        // zero Xp: 696,960 int4 units
        int bz = bx - 5426;                          // 681 blocks
        #pragma unroll
        for (int j = 0; j < 4; ++j) {
            int u = bz * 1024 + j * 256 + tid;
            if (u < 696960) {
                int4 z = {0, 0, 0, 0};
                ((int4*)Xp)[u] = z;
            }
        }
    }
}

// ---------------------------------------------------------------------------
// Gather (round-7/8-verified): stage 8 bf16 x-planes once; emit bilinear
// im2col (9 stores/px) + padded pack-8 x copy (1 store/px).
__global__ __launch_bounds__(256) void k_gather(const float* __restrict__ x,
                                                const uint32_t* __restrict__ oIdx,
                                                const float* __restrict__ oW,
                                                unsigned short* __restrict__ Sd,
                                                unsigned short* __restrict__ Xp)
{
    __shared__ __align__(16) uint32_t pl32[4096 * 4];   // 64 KB
    const int tid = threadIdx.x;
    const int split = blockIdx.x, gl = blockIdx.y, b = blockIdx.z;
    const float* xb = x + ((size_t)b * 320 + gl * 8) * 4096;
    #pragma unroll 8
    for (int it = 0; it < 64; ++it) {
        int u = it * 256 + tid;
        int p = u & 3, px = u >> 2;
        float va = xb[(size_t)(2 * p) * 4096 + px];
        float vb = xb[(size_t)(2 * p + 1) * 4096 + px];
        pl32[px * 4 + p] = pack2(va, vb);
    }
    __syncthreads();

    for (int i = 0; i < 4; ++i) {
        int px = split * 1024 + i * 256 + tid;
        int nb = b * 4096 + px;
        int row = px >> 6, col = px & 63;
        {
            int4 st = *(const int4*)&pl32[px * 4];
            size_t a = ((size_t)(gl * 4 + b) * 4356 + (row + 1) * 66 + (col + 1)) * 8;
            *(int4*)(Xp + a) = st;
        }
        #pragma unroll
        for (int k = 0; k < 9; ++k) {
            int gi = k * 4096 + px;
            uint32_t i0 = oIdx[gi * 2], i1 = oIdx[gi * 2 + 1];
            float4 w = *(const float4*)&oW[gi * 4];
            int4 t0 = *(const int4*)&pl32[(i0 & 0xFFFFu) * 4];
            int4 t1 = *(const int4*)&pl32[(i0 >> 16) * 4];
            int4 t2 = *(const int4*)&pl32[(i1 & 0xFFFFu) * 4];
            int4 t3 = *(const int4*)&pl32[(i1 >> 16) * 4];
            float ac[8];
            #pragma unroll
            for (int q = 0; q < 8; ++q) ac[q] = 0.f;
#define TAP(tv, wv) \
    ac[0] += wv * b2f_lo((uint32_t)tv.x); ac[1] += wv * b2f_hi((uint32_t)tv.x); \
    ac[2] += wv * b2f_lo((uint32_t)tv.y); ac[3] += wv * b2f_hi((uint32_t)tv.y); \
    ac[4] += wv * b2f_lo((uint32_t)tv.z); ac[5] += wv * b2f_hi((uint32_t)tv.z); \
    ac[6] += wv * b2f_lo((uint32_t)tv.w); ac[7] += wv * b2f_hi((uint32_t)tv.w);
            TAP(t0, w.x) TAP(t1, w.y) TAP(t2, w.z) TAP(t3, w.w)
#undef TAP
            int4 st;
            st.x = (int)pack2(ac[0], ac[1]);
            st.y = (int)pack2(ac[2], ac[3]);
            st.z = (int)pack2(ac[4], ac[5]);
            st.w = (int)pack2(ac[6], ac[7]);
            *(int4*)(Sd + ((size_t)(gl * 9 + k) * 16384 + nb) * 8) = st;
        }
    }
}

// ---------------------------------------------------------------------------
// MFMA GEMM, K=2880 as 45 BK=64 steps, fp32 register acc. BM=BN=128,
// 4 waves 2x2. A stored [kq][m] in LDS -> conflict-free ds_read_b128.
// All-pad wave tiles (rows>=320) skip fragment loads + MFMA + C-write.
__global__ __launch_bounds__(256) void k_gemm(const unsigned short* __restrict__ Sd,
                                              const unsigned short* __restrict__ Xp,
                                              const int* __restrict__ hoffG,
                                              const unsigned short* __restrict__ Wr,
                                              unsigned short* __restrict__ Cc,
                                              const float* __restrict__ bias)
{
    __shared__ __align__(16) unsigned short As[128 * 64];   // 16 KB, [kq 8][m 128][8]
    __shared__ __align__(16) unsigned short Bs[64 * 128];   // 16 KB, [row 8][n 128][8]
    const int tid = threadIdx.x;
    const int n0 = blockIdx.x * 128, m0 = blockIdx.y * 128;
    const int lane = tid & 63, w = tid >> 6;
    const int wm = w & 1, wn = w >> 1;
    const int quad = lane >> 4, nl = lane & 15;
    const bool hHalf = (n0 >= 16384);
    const bool mActive = (m0 + wm * 64) < 320;
    int xbase;
    {
        int nn = (n0 - 16384) + (tid & 127);
        int b = nn >> 12, px = nn & 4095;
        xbase = (b * 4356 + (px >> 6) * 66 + (px & 63)) * 8;
    }
    f32x4 acc[4][4];
    #pragma unroll
    for (int mt = 0; mt < 4; ++mt)
        #pragma unroll
        for (int nt = 0; nt < 4; ++nt)
            acc[mt][nt] = 0.f;

    for (int s = 0; s < 45; ++s) {
        __syncthreads();
        #pragma unroll
        for (int q = 0; q < 4; ++q) {
            int u = tid + q * 256;
            int kq = u >> 7, m = u & 127;            // [kq][m] LDS order
            gl_lds16(Wr + (size_t)(m0 + m) * 2880 + s * 64 + kq * 8, &As[u * 8]);
        }
        if (!hHalf) {
            #pragma unroll
            for (int q = 0; q < 4; ++q) {
                int u = tid + q * 256;
                int row = u >> 7, nn = n0 + (u & 127);
                gl_lds16(Sd + ((size_t)(s * 8 + row) * 16384 + nn) * 8, &Bs[u * 8]);
            }
        } else {
            #pragma unroll
            for (int q = 0; q < 4; ++q) {
                int u = tid + q * 256;
                int kkb = s * 8 + (u >> 7);          // wave-uniform
                int off = hoffG[__builtin_amdgcn_readfirstlane(kkb)];
                gl_lds16(Xp + (size_t)(xbase + off), &Bs[u * 8]);
            }
        }
        __syncthreads();
        if (mActive) {
            #pragma unroll
            for (int kc = 0; kc < 2; ++kc) {
                bf16x8 a[4], bf[4];
                #pragma unroll
                for (int mt = 0; mt < 4; ++mt)
                    a[mt] = *(const bf16x8*)&As[((kc * 4 + quad) * 128 + wm * 64 + mt * 16 + nl) * 8];
                #pragma unroll
                for (int nt = 0; nt < 4; ++nt)
                    bf[nt] = *(const bf16x8*)&Bs[((kc * 4 + quad) * 128 + wn * 64 + nt * 16 + nl) * 8];
                #pragma unroll
                for (int mt = 0; mt < 4; ++mt)
                    #pragma unroll
                    for (int nt = 0; nt < 4; ++nt)
                        acc[mt][nt] = __builtin_amdgcn_mfma_f32_16x16x32_bf16(a[mt], bf[nt], acc[mt][nt], 0, 0, 0);
            }
        }
    }

    if (mActive) {
        #pragma unroll
        for (int mt = 0; mt < 4; ++mt) {
            int o0 = m0 + wm * 64 + mt * 16 + quad * 4;
            float b0 = (o0 + 0 < 320) ? bias[o0 + 0] : 0.f;
            float b1 = (o0 + 1 < 320) ? bias[o0 + 1] : 0.f;
            float b2 = (o0 + 2 < 320) ? bias[o0 + 2] : 0.f;
            float b3 = (o0 + 3 < 320) ? bias[o0 + 3] : 0.f;
            #pragma unroll
            for (int nt = 0; nt < 4; ++nt) {
                int n2 = n0 + wn * 64 + nt * 16 + nl;
                unsigned short* p = Cc + ((size_t)(o0 >> 3) * 32768 + n2) * 8 + (o0 & 7);
                ushort4 st;
                st.x = f2b(acc[mt][nt][0] + b0);
                st.y = f2b(acc[mt][nt][1] + b1);
                st.z = f2b(acc[mt][nt][2] + b2);
                st.w = f2b(acc[mt][nt][3] + b3);
                *(ushort4*)p = st;
            }
        }
    }
}

// ---------------------------------------------------------------------------
// Final: out = h + scale * (W2 x [dconv; h]), K=640 as 10 BK=64 steps.
// Same conflict-free [kq][m] A layout.
__global__ __launch_bounds__(256) void k_final(const unsigned short* __restrict__ W2,
                                               const unsigned short* __restrict__ Cc,
                                               const float* __restrict__ scale,
                                               float* __restrict__ out)
{
    __shared__ __align__(16) unsigned short As[128 * 64];
    __shared__ __align__(16) unsigned short Bs[64 * 128];
    const int tid = threadIdx.x;
    const int n0 = blockIdx.x * 128, m0 = blockIdx.y * 128;
    const int lane = tid & 63, w = tid >> 6;
    const int wm = w & 1, wn = w >> 1;
    const int quad = lane >> 4, nl = lane & 15;
    const bool mActive = (m0 + wm * 64) < 320;
    f32x4 acc[4][4];
    #pragma unroll
    for (int mt = 0; mt < 4; ++mt)
        #pragma unroll
        for (int nt = 0; nt < 4; ++nt)
            acc[mt][nt] = 0.f;

    for (int s = 0; s < 10; ++s) {
        __syncthreads();
        #pragma unroll
        for (int q = 0; q < 4; ++q) {
            int u = tid + q * 256;
            int kq = u >> 7, m = u & 127;
            gl_lds16(W2 + (size_t)(m0 + m) * 640 + s * 64 + kq * 8, &As[u * 8]);
        }
        int h_off = (s < 5) ? 0 : 16384;
        int gq = (s < 5) ? s * 8 : (s - 5) * 8;
        #pragma unroll
        for (int q = 0; q < 4; ++q) {
            int u = tid + q * 256;
            int row = u >> 7, nn = n0 + (u & 127);
            gl_lds16(Cc + ((size_t)(gq + row) * 32768 + h_off + nn) * 8, &Bs[u * 8]);
        }
        __syncthreads();
        if (mActive) {
            #pragma unroll
            for (int kc = 0; kc < 2; ++kc) {
                bf16x8 a[4], bf[4];
                #pragma unroll
                for (int mt = 0; mt < 4; ++mt)
                    a[mt] = *(const bf16x8*)&As[((kc * 4 + quad) * 128 + wm * 64 + mt * 16 + nl) * 8];
                #pragma unroll
                for (int nt = 0; nt < 4; ++nt)
                    bf[nt] = *(const bf16x8*)&Bs[((kc * 4 + quad) * 128 + wn * 64 + nt * 16 + nl) * 8];
                #pragma unroll
                for (int mt = 0; mt < 4; ++mt)
                    #pragma unroll
                    for (int nt = 0; nt < 4; ++nt)
                        acc[mt][nt] = __builtin_amdgcn_mfma_f32_16x16x32_bf16(a[mt], bf[nt], acc[mt][nt], 0, 0, 0);
            }
        }
    }

    float sc = scale[0];
    if (mActive) {
        #pragma unroll
        for (int mt = 0; mt < 4; ++mt) {
            int o0 = m0 + wm * 64 + mt * 16 + quad * 4;
            if (o0 >= 320) continue;
            #pragma unroll
            for (int nt = 0; nt < 4; ++nt) {
                int n = n0 + wn * 64 + nt * 16 + nl;
                int b = n >> 12, px = n & 4095;
                ushort4 hv = *(const ushort4*)(Cc + ((size_t)(o0 >> 3) * 32768 + n + 16384) * 8 + (o0 & 7));
                size_t base = ((size_t)(b * 320 + o0)) * 4096 + px;
                out[base]            = b2f(hv.x) + sc * acc[mt][nt][0];
                out[base + 4096]     = b2f(hv.y) + sc * acc[mt][nt][1];
                out[base + 2 * 4096] = b2f(hv.z) + sc * acc[mt][nt][2];
                out[base + 3 * 4096] = b2f(hv.w) + sc * acc[mt][nt][3];
            }
        }
    }
}

// ---------------------------------------------------------------------------
extern "C" void kernel_launch(void* const* d_in, const int* in_sizes, int n_in,
                              void* d_out, int out_size, void* d_ws, size_t ws_size,
                              hipStream_t stream)
{
    const float* x      = (const float*)d_in[0];
    const float* weight = (const float*)d_in[1];
    const float* bias   = (const float*)d_in[2];
    const float* w_down = (const float*)d_in[3];
    const float* w_up   = (const float*)d_in[4];
    const float* scale  = (const float*)d_in[5];
    const float* offset = (const float*)d_in[6];
    char* ws = (char*)d_ws;
    unsigned short* Cc    = (unsigned short*)(ws + 0);
    unsigned short* Wr    = (unsigned short*)(ws + 25165824);
    unsigned short* W2    = (unsigned short*)(ws + 27377664);
    uint32_t*       oI    = (uint32_t*)(ws + 27869184);
    float*          oWt   = (float*)(ws + 28164096);
    int*            hoffG = (int*)(ws + 28753920);
    unsigned short* Xp    = (unsigned short*)(ws + 28758016);
    unsigned short* Sd    = (unsigned short*)(ws + 39909376);
    float* out = (float*)d_out;

    hipLaunchKernelGGL(k_prep, dim3(6107), dim3(256), 0, stream,
                       offset, weight, w_down, w_up, oI, oWt, Wr, W2, hoffG, Xp);
    hipLaunchKernelGGL(k_gather, dim3(4, 40, 4), dim3(256), 0, stream,
                       x, oI, oWt, Sd, Xp);
    hipLaunchKernelGGL(k_gemm, dim3(256, 3), dim3(256), 0, stream,
                       Sd, Xp, hoffG, Wr, Cc, bias);
    hipLaunchKernelGGL(k_final, dim3(128, 3), dim3(256), 0, stream,
                       W2, Cc, scale, out);
}

// Round 10
// 237.590 us; speedup vs baseline: 1.2106x; 1.2106x over previous
//
#include <hip/hip_runtime.h>
#include <stdint.h>

// B=4, C=O=320, H=W=64 -> HW=4096, N2=32768 (dconv n<16384, h n>=16384),
// K=2880 (M pad 384), Kf=640.
// K-permutation: kk = g*72 + k*8 + cl, c = g*8+cl (g<40, k<9, cl<8); kkb=kk>>3=g*9+k.
// Sd packed-8 (dconv only): elem(kk,n) at ushort idx (kkb*16384+n)*8 + (kk&7).
// Xp (padded x, h half): [g][b][py 66][px 66][cl 8] bf16; interior = x, halo = 0.
// Cc packed-8: elem(o,n2) at (o>>3)*32768*8 + n2*8 + (o&7).
// Wr K-major packed-8: elem(o,kk) at (kkb*384 + o)*8 + (kk&7)  <- coalesced
//   A-staging AND conflict-free [kq][m] LDS in one layout. W2 likewise (Kf).
//
// ws layout (bytes):
//   Cc 0..25,165,824 | Wr ..27,377,664 | W2 ..27,869,184 | oI ..28,164,096
//   oWt ..28,753,920 | hoffG ..28,758,016 | Xp ..39,909,376 | Sd ..134,281,216

typedef __attribute__((ext_vector_type(4))) float f32x4;
typedef __attribute__((ext_vector_type(8))) short bf16x8;

typedef __attribute__((address_space(1))) const unsigned int uint_as1;
typedef __attribute__((address_space(3))) unsigned int uint_as3;

__device__ __forceinline__ void gl_lds16(const void* g, void* l) {
    __builtin_amdgcn_global_load_lds((uint_as1*)g, (uint_as3*)l, 16, 0, 0);
}

__device__ __forceinline__ unsigned short f2b(float f) {
    union { float f; uint32_t u; } v; v.f = f;
    uint32_t r = (v.u + 0x7FFFu + ((v.u >> 16) & 1u)) >> 16;
    return (unsigned short)r;
}
__device__ __forceinline__ float b2f(unsigned short h) {
    union { uint32_t u; float f; } v; v.u = ((uint32_t)h) << 16;
    return v.f;
}
__device__ __forceinline__ float b2f_lo(uint32_t u) {
    union { uint32_t u; float f; } v; v.u = u << 16;
    return v.f;
}
__device__ __forceinline__ float b2f_hi(uint32_t u) {
    union { uint32_t u; float f; } v; v.u = u & 0xFFFF0000u;
    return v.f;
}
__device__ __forceinline__ uint32_t pack2(float lo, float hi) {
    return (uint32_t)f2b(lo) | ((uint32_t)f2b(hi) << 16);
}

// ---------------------------------------------------------------------------
// Fused prep. [0,144) bilinear; [144,4464) Wr (K-major packed-8);
// [4464,5424) W2 (K-major packed-8); [5424,5426) hoffG; [5426,6107) zero Xp.
__global__ __launch_bounds__(256) void k_prep(const float* __restrict__ off,
                                              const float* __restrict__ w,
                                              const float* __restrict__ wd,
                                              const float* __restrict__ wu,
                                              uint32_t* __restrict__ oIdx,
                                              float* __restrict__ oW,
                                              unsigned short* __restrict__ Wr,
                                              unsigned short* __restrict__ W2,
                                              int* __restrict__ hoffG,
                                              unsigned short* __restrict__ Xp)
{
    const int bx = blockIdx.x, tid = threadIdx.x;
    if (bx < 144) {
        int gid = bx * 256 + tid;                    // 9*4096 exact
        int k = gid >> 12;
        int p = gid & 4095;
        int i = p >> 6, j = p & 63;
        float dy = off[(2 * k) * 4096 + p];
        float dx = off[(2 * k + 1) * 4096 + p];
        float py = (float)(i - 1 + k / 3) + dy;
        float px = (float)(j - 1 + k % 3) + dx;
        float fy = floorf(py), fx = floorf(px);
        float wy = py - fy, wx = px - fx;
        fy = fminf(fmaxf(fy, -100.f), 100.f);
        fx = fminf(fmaxf(fx, -100.f), 100.f);
        int y0 = (int)fy, x0 = (int)fx;
        float vy0 = (y0 >= 0 && y0 < 64) ? 1.f : 0.f;
        float vy1 = (y0 >= -1 && y0 < 63) ? 1.f : 0.f;
        float vx0 = (x0 >= 0 && x0 < 64) ? 1.f : 0.f;
        float vx1 = (x0 >= -1 && x0 < 63) ? 1.f : 0.f;
        float w00 = (1.f - wy) * (1.f - wx) * vy0 * vx0;
        float w01 = (1.f - wy) * wx * vy0 * vx1;
        float w10 = wy * (1.f - wx) * vy1 * vx0;
        float w11 = wy * wx * vy1 * vx1;
        int ya = min(max(y0, 0), 63), yb = min(max(y0 + 1, 0), 63);
        int xa = min(max(x0, 0), 63), xb = min(max(x0 + 1, 0), 63);
        oIdx[gid * 2 + 0] = (uint32_t)(ya * 64 + xa) | ((uint32_t)(ya * 64 + xb) << 16);
        oIdx[gid * 2 + 1] = (uint32_t)(yb * 64 + xa) | ((uint32_t)(yb * 64 + xb) << 16);
        oW[gid * 4 + 0] = w00;
        oW[gid * 4 + 1] = w01;
        oW[gid * 4 + 2] = w10;
        oW[gid * 4 + 3] = w11;
    } else if (bx < 4464) {
        int gid = (bx - 144) * 256 + tid;            // 384*2880 exact
        int o = gid / 2880, kk = gid % 2880;
        int g = kk / 72, r = kk % 72, k = r >> 3, cl = r & 7, c = g * 8 + cl;
        float v = (o < 320) ? w[((size_t)o * 320 + c) * 9 + k] : 0.f;
        Wr[(size_t)((kk >> 3) * 384 + o) * 8 + (kk & 7)] = f2b(v);
    } else if (bx < 5424) {
        int gid = (bx - 4464) * 256 + tid;           // 384*640 exact
        int o = gid / 640, kk2 = gid % 640;
        float acc = 0.f;
        if (o < 320) {
            for (int l = 0; l < 320; ++l)
                acc += wu[o * 320 + l] * wd[l * 640 + kk2];
        }
        W2[(size_t)((kk2 >> 3) * 384 + o) * 8 + (kk2 & 7)] = f2b(acc);
    } else if (bx < 5426) {
        int kkb = (bx - 5424) * 256 + tid;           // 360 entries
        if (kkb < 360) {
            int g = kkb / 9, k = kkb % 9;
            hoffG[kkb] = (g * 17424 + (k / 3) * 66 + (k % 3)) * 8; // ushort units
        }
    } else {
        // zero Xp: 696,960 int4 units
        int bz = bx - 5426;                          // 681 blocks
        #pragma unroll
        for (int j = 0; j < 4; ++j) {
            int u = bz * 1024 + j * 256 + tid;
            if (u < 696960) {
                int4 z = {0, 0, 0, 0};
                ((int4*)Xp)[u] = z;
            }
        }
    }
}

// ---------------------------------------------------------------------------
// Gather (rounds-7..9-verified): stage 8 bf16 x-planes once; emit bilinear
// im2col (9 stores/px) + padded pack-8 x copy (1 store/px).
__global__ __launch_bounds__(256) void k_gather(const float* __restrict__ x,
                                                const uint32_t* __restrict__ oIdx,
                                                const float* __restrict__ oW,
                                                unsigned short* __restrict__ Sd,
                                                unsigned short* __restrict__ Xp)
{
    __shared__ __align__(16) uint32_t pl32[4096 * 4];   // 64 KB
    const int tid = threadIdx.x;
    const int split = blockIdx.x, gl = blockIdx.y, b = blockIdx.z;
    const float* xb = x + ((size_t)b * 320 + gl * 8) * 4096;
    #pragma unroll 8
    for (int it = 0; it < 64; ++it) {
        int u = it * 256 + tid;
        int p = u & 3, px = u >> 2;
        float va = xb[(size_t)(2 * p) * 4096 + px];
        float vb = xb[(size_t)(2 * p + 1) * 4096 + px];
        pl32[px * 4 + p] = pack2(va, vb);
    }
    __syncthreads();

    for (int i = 0; i < 4; ++i) {
        int px = split * 1024 + i * 256 + tid;
        int nb = b * 4096 + px;
        int row = px >> 6, col = px & 63;
        {
            int4 st = *(const int4*)&pl32[px * 4];
            size_t a = ((size_t)(gl * 4 + b) * 4356 + (row + 1) * 66 + (col + 1)) * 8;
            *(int4*)(Xp + a) = st;
        }
        #pragma unroll
        for (int k = 0; k < 9; ++k) {
            int gi = k * 4096 + px;
            uint32_t i0 = oIdx[gi * 2], i1 = oIdx[gi * 2 + 1];
            float4 w = *(const float4*)&oW[gi * 4];
            int4 t0 = *(const int4*)&pl32[(i0 & 0xFFFFu) * 4];
            int4 t1 = *(const int4*)&pl32[(i0 >> 16) * 4];
            int4 t2 = *(const int4*)&pl32[(i1 & 0xFFFFu) * 4];
            int4 t3 = *(const int4*)&pl32[(i1 >> 16) * 4];
            float ac[8];
            #pragma unroll
            for (int q = 0; q < 8; ++q) ac[q] = 0.f;
#define TAP(tv, wv) \
    ac[0] += wv * b2f_lo((uint32_t)tv.x); ac[1] += wv * b2f_hi((uint32_t)tv.x); \
    ac[2] += wv * b2f_lo((uint32_t)tv.y); ac[3] += wv * b2f_hi((uint32_t)tv.y); \
    ac[4] += wv * b2f_lo((uint32_t)tv.z); ac[5] += wv * b2f_hi((uint32_t)tv.z); \
    ac[6] += wv * b2f_lo((uint32_t)tv.w); ac[7] += wv * b2f_hi((uint32_t)tv.w);
            TAP(t0, w.x) TAP(t1, w.y) TAP(t2, w.z) TAP(t3, w.w)
#undef TAP
            int4 st;
            st.x = (int)pack2(ac[0], ac[1]);
            st.y = (int)pack2(ac[2], ac[3]);
            st.z = (int)pack2(ac[4], ac[5]);
            st.w = (int)pack2(ac[6], ac[7]);
            *(int4*)(Sd + ((size_t)(gl * 9 + k) * 16384 + nb) * 8) = st;
        }
    }
}

// ---------------------------------------------------------------------------
// MFMA GEMM, K=2880 as 45 BK=64 steps, fp32 register acc. BM=BN=128,
// 4 waves 2x2. A: K-major packed-8 global -> coalesced stage -> [kq][m] LDS
// (conflict-free). All-pad wave tiles (rows>=320) skip compute.
__global__ __launch_bounds__(256) void k_gemm(const unsigned short* __restrict__ Sd,
                                              const unsigned short* __restrict__ Xp,
                                              const int* __restrict__ hoffG,
                                              const unsigned short* __restrict__ Wr,
                                              unsigned short* __restrict__ Cc,
                                              const float* __restrict__ bias)
{
    __shared__ __align__(16) unsigned short As[128 * 64];   // [kq 8][m 128][8]
    __shared__ __align__(16) unsigned short Bs[64 * 128];   // [row 8][n 128][8]
    const int tid = threadIdx.x;
    const int n0 = blockIdx.x * 128, m0 = blockIdx.y * 128;
    const int lane = tid & 63, w = tid >> 6;
    const int wm = w & 1, wn = w >> 1;
    const int quad = lane >> 4, nl = lane & 15;
    const bool hHalf = (n0 >= 16384);
    const bool mActive = (m0 + wm * 64) < 320;
    int xbase;
    {
        int nn = (n0 - 16384) + (tid & 127);
        int b = nn >> 12, px = nn & 4095;
        xbase = (b * 4356 + (px >> 6) * 66 + (px & 63)) * 8;
    }
    f32x4 acc[4][4];
    #pragma unroll
    for (int mt = 0; mt < 4; ++mt)
        #pragma unroll
        for (int nt = 0; nt < 4; ++nt)
            acc[mt][nt] = 0.f;

    for (int s = 0; s < 45; ++s) {
        __syncthreads();
        #pragma unroll
        for (int q = 0; q < 4; ++q) {
            int u = tid + q * 256;
            int kq = u >> 7, m = u & 127;            // consecutive lanes -> consecutive m
            gl_lds16(Wr + ((size_t)(s * 8 + kq) * 384 + m0 + m) * 8, &As[u * 8]);
        }
        if (!hHalf) {
            #pragma unroll
            for (int q = 0; q < 4; ++q) {
                int u = tid + q * 256;
                int row = u >> 7, nn = n0 + (u & 127);
                gl_lds16(Sd + ((size_t)(s * 8 + row) * 16384 + nn) * 8, &Bs[u * 8]);
            }
        } else {
            #pragma unroll
            for (int q = 0; q < 4; ++q) {
                int u = tid + q * 256;
                int kkb = s * 8 + (u >> 7);          // wave-uniform
                int off = hoffG[__builtin_amdgcn_readfirstlane(kkb)];
                gl_lds16(Xp + (size_t)(xbase + off), &Bs[u * 8]);
            }
        }
        __syncthreads();
        if (mActive) {
            #pragma unroll
            for (int kc = 0; kc < 2; ++kc) {
                bf16x8 a[4], bf[4];
                #pragma unroll
                for (int mt = 0; mt < 4; ++mt)
                    a[mt] = *(const bf16x8*)&As[((kc * 4 + quad) * 128 + wm * 64 + mt * 16 + nl) * 8];
                #pragma unroll
                for (int nt = 0; nt < 4; ++nt)
                    bf[nt] = *(const bf16x8*)&Bs[((kc * 4 + quad) * 128 + wn * 64 + nt * 16 + nl) * 8];
                #pragma unroll
                for (int mt = 0; mt < 4; ++mt)
                    #pragma unroll
                    for (int nt = 0; nt < 4; ++nt)
                        acc[mt][nt] = __builtin_amdgcn_mfma_f32_16x16x32_bf16(a[mt], bf[nt], acc[mt][nt], 0, 0, 0);
            }
        }
    }

    if (mActive) {
        #pragma unroll
        for (int mt = 0; mt < 4; ++mt) {
            int o0 = m0 + wm * 64 + mt * 16 + quad * 4;
            float b0 = (o0 + 0 < 320) ? bias[o0 + 0] : 0.f;
            float b1 = (o0 + 1 < 320) ? bias[o0 + 1] : 0.f;
            float b2 = (o0 + 2 < 320) ? bias[o0 + 2] : 0.f;
            float b3 = (o0 + 3 < 320) ? bias[o0 + 3] : 0.f;
            #pragma unroll
            for (int nt = 0; nt < 4; ++nt) {
                int n2 = n0 + wn * 64 + nt * 16 + nl;
                unsigned short* p = Cc + ((size_t)(o0 >> 3) * 32768 + n2) * 8 + (o0 & 7);
                ushort4 st;
                st.x = f2b(acc[mt][nt][0] + b0);
                st.y = f2b(acc[mt][nt][1] + b1);
                st.z = f2b(acc[mt][nt][2] + b2);
                st.w = f2b(acc[mt][nt][3] + b3);
                *(ushort4*)p = st;
            }
        }
    }
}

// ---------------------------------------------------------------------------
// Final: out = h + scale * (W2 x [dconv; h]), K=640 as 10 BK=64 steps.
// W2 K-major packed-8 -> coalesced stage -> conflict-free [kq][m] LDS.
__global__ __launch_bounds__(256) void k_final(const unsigned short* __restrict__ W2,
                                               const unsigned short* __restrict__ Cc,
                                               const float* __restrict__ scale,
                                               float* __restrict__ out)
{
    __shared__ __align__(16) unsigned short As[128 * 64];
    __shared__ __align__(16) unsigned short Bs[64 * 128];
    const int tid = threadIdx.x;
    const int n0 = blockIdx.x * 128, m0 = blockIdx.y * 128;
    const int lane = tid & 63, w = tid >> 6;
    const int wm = w & 1, wn = w >> 1;
    const int quad = lane >> 4, nl = lane & 15;
    const bool mActive = (m0 + wm * 64) < 320;
    f32x4 acc[4][4];
    #pragma unroll
    for (int mt = 0; mt < 4; ++mt)
        #pragma unroll
        for (int nt = 0; nt < 4; ++nt)
            acc[mt][nt] = 0.f;

    for (int s = 0; s < 10; ++s) {
        __syncthreads();
        #pragma unroll
        for (int q = 0; q < 4; ++q) {
            int u = tid + q * 256;
            int kq = u >> 7, m = u & 127;
            gl_lds16(W2 + ((size_t)(s * 8 + kq) * 384 + m0 + m) * 8, &As[u * 8]);
        }
        int h_off = (s < 5) ? 0 : 16384;
        int gq = (s < 5) ? s * 8 : (s - 5) * 8;
        #pragma unroll
        for (int q = 0; q < 4; ++q) {
            int u = tid + q * 256;
            int row = u >> 7, nn = n0 + (u & 127);
            gl_lds16(Cc + ((size_t)(gq + row) * 32768 + h_off + nn) * 8, &Bs[u * 8]);
        }
        __syncthreads();
        if (mActive) {
            #pragma unroll
            for (int kc = 0; kc < 2; ++kc) {
                bf16x8 a[4], bf[4];
                #pragma unroll
                for (int mt = 0; mt < 4; ++mt)
                    a[mt] = *(const bf16x8*)&As[((kc * 4 + quad) * 128 + wm * 64 + mt * 16 + nl) * 8];
                #pragma unroll
                for (int nt = 0; nt < 4; ++nt)
                    bf[nt] = *(const bf16x8*)&Bs[((kc * 4 + quad) * 128 + wn * 64 + nt * 16 + nl) * 8];
                #pragma unroll
                for (int mt = 0; mt < 4; ++mt)
                    #pragma unroll
                    for (int nt = 0; nt < 4; ++nt)
                        acc[mt][nt] = __builtin_amdgcn_mfma_f32_16x16x32_bf16(a[mt], bf[nt], acc[mt][nt], 0, 0, 0);
            }
        }
    }

    float sc = scale[0];
    if (mActive) {
        #pragma unroll
        for (int mt = 0; mt < 4; ++mt) {
            int o0 = m0 + wm * 64 + mt * 16 + quad * 4;
            if (o0 >= 320) continue;
            #pragma unroll
            for (int nt = 0; nt < 4; ++nt) {
                int n = n0 + wn * 64 + nt * 16 + nl;
                int b = n >> 12, px = n & 4095;
                ushort4 hv = *(const ushort4*)(Cc + ((size_t)(o0 >> 3) * 32768 + n + 16384) * 8 + (o0 & 7));
                size_t base = ((size_t)(b * 320 + o0)) * 4096 + px;
                out[base]            = b2f(hv.x) + sc * acc[mt][nt][0];
                out[base + 4096]     = b2f(hv.y) + sc * acc[mt][nt][1];
                out[base + 2 * 4096] = b2f(hv.z) + sc * acc[mt][nt][2];
                out[base + 3 * 4096] = b2f(hv.w) + sc * acc[mt][nt][3];
            }
        }
    }
}

// ---------------------------------------------------------------------------
extern "C" void kernel_launch(void* const* d_in, const int* in_sizes, int n_in,
                              void* d_out, int out_size, void* d_ws, size_t ws_size,
                              hipStream_t stream)
{
    const float* x      = (const float*)d_in[0];
    const float* weight = (const float*)d_in[1];
    const float* bias   = (const float*)d_in[2];
    const float* w_down = (const float*)d_in[3];
    const float* w_up   = (const float*)d_in[4];
    const float* scale  = (const float*)d_in[5];
    const float* offset = (const float*)d_in[6];
    char* ws = (char*)d_ws;
    unsigned short* Cc    = (unsigned short*)(ws + 0);
    unsigned short* Wr    = (unsigned short*)(ws + 25165824);
    unsigned short* W2    = (unsigned short*)(ws + 27377664);
    uint32_t*       oI    = (uint32_t*)(ws + 27869184);
    float*          oWt   = (float*)(ws + 28164096);
    int*            hoffG = (int*)(ws + 28753920);
    unsigned short* Xp    = (unsigned short*)(ws + 28758016);
    unsigned short* Sd    = (unsigned short*)(ws + 39909376);
    float* out = (float*)d_out;

    hipLaunchKernelGGL(k_prep, dim3(6107), dim3(256), 0, stream,
                       offset, weight, w_down, w_up, oI, oWt, Wr, W2, hoffG, Xp);
    hipLaunchKernelGGL(k_gather, dim3(4, 40, 4), dim3(256), 0, stream,
                       x, oI, oWt, Sd, Xp);
    hipLaunchKernelGGL(k_gemm, dim3(256, 3), dim3(256), 0, stream,
                       Sd, Xp, hoffG, Wr, Cc, bias);
    hipLaunchKernelGGL(k_final, dim3(128, 3), dim3(256), 0, stream,
                       W2, Cc, scale, out);
}